// Round 5
// baseline (455.271 us; speedup 1.0000x reference)
//
#include <hip/hip_runtime.h>

typedef __attribute__((ext_vector_type(8))) short  short8v;
typedef __attribute__((ext_vector_type(4))) float  float4v;

#define BDIM 512

// Pre-converted, pre-swizzled bf16 weights: [p(3)][kb(8)][n(256)][c(8)][j(8)]
// content: B_p[n][kb*64 + (c ^ (n&7))*8 + j], B_p = [W_p | U_p] (K-concat, 512 wide)
__device__ ushort g_w[3 * 8 * 2048 * 8];

__device__ __forceinline__ ushort f2bf(float f) {
  unsigned u = __float_as_uint(f);
  u += 0x7fffu + ((u >> 16) & 1u);          // round-to-nearest-even
  return (ushort)(u >> 16);
}
__device__ __forceinline__ float bf2f(ushort s) {
  return __uint_as_float(((unsigned)s) << 16);
}

__global__ __launch_bounds__(256) void conv_w(
    const float* __restrict__ Wz, const float* __restrict__ Uz,
    const float* __restrict__ Wa, const float* __restrict__ Ua,
    const float* __restrict__ Wh, const float* __restrict__ Uh)
{
  int tid = blockIdx.x * 256 + threadIdx.x;   // 49152 total
  int p  = tid >> 14;
  int rm = tid & 16383;
  int kb = rm >> 11;
  int n  = (rm >> 3) & 255;
  int c  = rm & 7;
  const float* W = (p == 0) ? Wz : (p == 1) ? Wa : Wh;
  const float* U = (p == 0) ? Uz : (p == 1) ? Ua : Uh;
  int k0 = kb * 64 + ((c ^ (n & 7)) << 3);    // 8-aligned, never straddles 256
  const float* src = (k0 < 256) ? (W + n * 256 + k0) : (U + n * 256 + k0 - 256);
  uint pk[4];
#pragma unroll
  for (int jj = 0; jj < 4; ++jj) {
    float v0 = src[jj * 2], v1 = src[jj * 2 + 1];
    pk[jj] = (uint)f2bf(v0) | ((uint)f2bf(v1) << 16);
  }
  *reinterpret_cast<uint4*>(&g_w[(size_t)tid * 8]) = make_uint4(pk[0], pk[1], pk[2], pk[3]);
}

// LDS caps us at 1 WG/CU (132 KB) = 2 waves/SIMD. Tell the allocator so it
// uses the full 256-VGPR budget instead of squeezing to 128 and spilling.
__global__ __launch_bounds__(BDIM) __attribute__((amdgpu_waves_per_eu(2, 2)))
void gru_fused(
    const float* __restrict__ x,  const float* __restrict__ hp,
    const float* __restrict__ bz, const float* __restrict__ va,
    const float* __restrict__ bh, float* __restrict__ out)
{
  // A-tile: [64 rows][512 K] bf16, 16B-chunk XOR swizzle  (64 KB)
  __shared__ __align__(16) ushort sA[64 * 512];
  // B-tile: double-buffered [256 n][64 K] bf16, pre-swizzled in g_w  (2 x 32 KB)
  __shared__ __align__(16) ushort sB[2][256 * 64];
  __shared__ __align__(16) float  sRed[2][64 * 8];   // softmax cross-wave scratch

  const int tid  = threadIdx.x;
  const int w    = tid >> 6;       // wave 0..7, owns cols [w*32, w*32+32)
  const int lane = tid & 63;
  const int g4   = lane >> 4;
  const int l15  = lane & 15;
  const int sxor = l15 & 7;        // row&7 == n&7 == l15&7 for all frag rows
  const int rowBlk = blockIdx.x << 6;

  auto stageB = [&](int blkid, int buf) {
    const char* sb = (const char*)g_w + ((size_t)blkid << 15) + (w << 12) + (lane << 4);
    char* db = ((char*)&sB[buf][0]) + (w << 12);
#pragma unroll
    for (int i = 0; i < 4; ++i) {
      __builtin_amdgcn_global_load_lds(
          (const __attribute__((address_space(1))) void*)(sb + i * 1024),
          (__attribute__((address_space(3))) void*)(db + i * 1024),
          16, 0, 0);
    }
  };

  stageB(0, 0);   // phase 0, kb 0 -> buf 0

  { // stage A = [x | h] as bf16, swizzled
    const float4* xq = reinterpret_cast<const float4*>(x)  + (size_t)rowBlk * 64;
    const float4* hq = reinterpret_cast<const float4*>(hp) + (size_t)rowBlk * 64;
#pragma unroll
    for (int i = 0; i < 16; ++i) {
      int q   = tid + i * BDIM;        // 0..8191 quad index
      int row = q >> 7;
      int qc  = q & 127;
      float4 v = (qc < 64) ? xq[row * 64 + qc] : hq[row * 64 + qc - 64];
      int kE  = qc << 2;
      int swz = (kE >> 3) ^ (row & 7);
      ushort4 pk4;
      pk4.x = f2bf(v.x); pk4.y = f2bf(v.y); pk4.z = f2bf(v.z); pk4.w = f2bf(v.w);
      *reinterpret_cast<ushort4*>((char*)sA + (row << 10) + (swz << 4) + ((kE & 7) << 1)) = pk4;
    }
  }
  __syncthreads();   // full drain: sA + stage(0) complete

  float4v acc[4][2];
  float   zf[4][2][4];   // z gate, phase-1 result (C-layout positions match phase 3)
  float   hv[4][2][4];   // h_prev at C-layout positions (bf16-rounded)
  int cur = 0;

  for (int p = 0; p < 3; ++p) {
#pragma unroll
    for (int m = 0; m < 4; ++m)
#pragma unroll
      for (int r = 0; r < 2; ++r)
        acc[m][r] = (float4v){0.f, 0.f, 0.f, 0.f};

    for (int kb = 0; kb < 8; ++kb) {
      int blk = p * 8 + kb;
      // Stage next K-block into cur^1. Readers of cur^1 all retired at the
      // s_barrier that ended the previous iteration, so writes are race-free.
      // Counted gate: keep the 4 just-issued loads in flight, drain the 4
      // older ones that filled buffer `cur` (T4 — never vmcnt(0) mid-loop).
      if (blk < 23) {
        stageB(blk + 1, cur ^ 1);
        asm volatile("s_waitcnt vmcnt(4)" ::: "memory");
      } else {
        asm volatile("s_waitcnt vmcnt(0)" ::: "memory");
      }

      short8v afr[2][4], bfr[2][2];
#pragma unroll
      for (int s = 0; s < 2; ++s) {
#pragma unroll
        for (int m = 0; m < 4; ++m) {
          int row = m * 16 + l15;
          int swz = (kb * 8 + s * 4 + g4) ^ sxor;
          afr[s][m] = *reinterpret_cast<const short8v*>((const char*)sA + (row << 10) + (swz << 4));
        }
#pragma unroll
        for (int r = 0; r < 2; ++r) {
          int n   = (w << 5) + (r << 4) + l15;
          int swz = (s * 4 + g4) ^ sxor;
          bfr[s][r] = *reinterpret_cast<const short8v*>((const char*)&sB[cur][0] + (n << 7) + (swz << 4));
        }
      }
#pragma unroll
      for (int s = 0; s < 2; ++s)
#pragma unroll
        for (int m = 0; m < 4; ++m)
#pragma unroll
          for (int r = 0; r < 2; ++r)
            acc[m][r] = __builtin_amdgcn_mfma_f32_16x16x32_bf16(afr[s][m], bfr[s][r], acc[m][r], 0, 0, 0);

      __builtin_amdgcn_s_barrier();   // window boundary (no vmcnt drain)
      cur ^= 1;
    }

    if (p == 0) {
      // z = sigmoid(pre + b_z)
#pragma unroll
      for (int r = 0; r < 2; ++r) {
        float b = bz[(w << 5) + (r << 4) + l15];
#pragma unroll
        for (int m = 0; m < 4; ++m)
#pragma unroll
          for (int j = 0; j < 4; ++j)
            zf[m][r][j] = 1.f / (1.f + __expf(-(acc[m][r][j] + b)));
      }
    } else if (p == 1) {
      // t = tanh(pre) * v_a ; softmax over 256 cols per row ; attended = aw*h
      float vav[2];
      vav[0] = va[(w << 5) + l15];
      vav[1] = va[(w << 5) + 16 + l15];
#pragma unroll
      for (int m = 0; m < 4; ++m)
#pragma unroll
        for (int r = 0; r < 2; ++r)
#pragma unroll
          for (int j = 0; j < 4; ++j) {
            float s = acc[m][r][j];
            float t = 1.f - 2.f / (__expf(2.f * s) + 1.f);
            acc[m][r][j] = t * vav[r];
          }
      // wave-local row max (16-lane groups share a row set)
      float mx[4][4];
#pragma unroll
      for (int m = 0; m < 4; ++m)
#pragma unroll
        for (int j = 0; j < 4; ++j) {
          float v = fmaxf(acc[m][0][j], acc[m][1][j]);
          v = fmaxf(v, __shfl_xor(v, 1));
          v = fmaxf(v, __shfl_xor(v, 2));
          v = fmaxf(v, __shfl_xor(v, 4));
          v = fmaxf(v, __shfl_xor(v, 8));
          mx[m][j] = v;
        }
      if (l15 == 0) {
#pragma unroll
        for (int m = 0; m < 4; ++m)
#pragma unroll
          for (int j = 0; j < 4; ++j)
            sRed[0][((m * 16 + g4 * 4 + j) << 3) + w] = mx[m][j];
      }
      __syncthreads();
      float rmax[4][4];
#pragma unroll
      for (int m = 0; m < 4; ++m)
#pragma unroll
        for (int j = 0; j < 4; ++j) {
          int row = m * 16 + g4 * 4 + j;
          const float4* pr = reinterpret_cast<const float4*>(&sRed[0][row << 3]);
          float4 a = pr[0], b = pr[1];
          rmax[m][j] = fmaxf(fmaxf(fmaxf(a.x, a.y), fmaxf(a.z, a.w)),
                             fmaxf(fmaxf(b.x, b.y), fmaxf(b.z, b.w)));
        }
#pragma unroll
      for (int m = 0; m < 4; ++m)
#pragma unroll
        for (int j = 0; j < 4; ++j) {
          float e0 = __expf(acc[m][0][j] - rmax[m][j]);
          float e1 = __expf(acc[m][1][j] - rmax[m][j]);
          acc[m][0][j] = e0; acc[m][1][j] = e1;
          float sm = e0 + e1;
          sm += __shfl_xor(sm, 1);
          sm += __shfl_xor(sm, 2);
          sm += __shfl_xor(sm, 4);
          sm += __shfl_xor(sm, 8);
          if (l15 == 0) sRed[1][((m * 16 + g4 * 4 + j) << 3) + w] = sm;
        }
      // load h (own positions) BEFORE overwriting h-half with attended
#pragma unroll
      for (int m = 0; m < 4; ++m)
#pragma unroll
        for (int r = 0; r < 2; ++r)
#pragma unroll
          for (int j = 0; j < 4; ++j) {
            int row = m * 16 + g4 * 4 + j;
            int cs  = (32 + (w << 2) + (r << 1) + (l15 >> 3)) ^ (row & 7);
            hv[m][r][j] = bf2f(sA[(row << 9) + (cs << 3) + sxor]);
          }
      __syncthreads();
#pragma unroll
      for (int m = 0; m < 4; ++m)
#pragma unroll
        for (int j = 0; j < 4; ++j) {
          int row = m * 16 + g4 * 4 + j;
          const float4* pr = reinterpret_cast<const float4*>(&sRed[1][row << 3]);
          float4 a = pr[0], b = pr[1];
          float s = (a.x + a.y) + (a.z + a.w) + (b.x + b.y) + (b.z + b.w);
          float inv = 1.f / s;
#pragma unroll
          for (int r = 0; r < 2; ++r) {
            float at = acc[m][r][j] * inv * hv[m][r][j];
            int cs = (32 + (w << 2) + (r << 1) + (l15 >> 3)) ^ (row & 7);
            sA[(row << 9) + (cs << 3) + sxor] = f2bf(at);
          }
        }
      __syncthreads();
    } else {
      // h~ = tanh(pre + b_h); h_t = (1-z)h + z h~
#pragma unroll
      for (int r = 0; r < 2; ++r) {
        float b = bh[(w << 5) + (r << 4) + l15];
#pragma unroll
        for (int m = 0; m < 4; ++m)
#pragma unroll
          for (int j = 0; j < 4; ++j) {
            float s  = acc[m][r][j] + b;
            float ht = 1.f - 2.f / (__expf(2.f * s) + 1.f);
            float z  = zf[m][r][j];
            float res = (1.f - z) * hv[m][r][j] + z * ht;
            int row = m * 16 + g4 * 4 + j;
            out[(size_t)(rowBlk + row) * 256 + (w << 5) + (r << 4) + l15] = res;
          }
      }
    }
  }
}

extern "C" void kernel_launch(void* const* d_in, const int* in_sizes, int n_in,
                              void* d_out, int out_size, void* d_ws, size_t ws_size,
                              hipStream_t stream)
{
  const float* x  = (const float*)d_in[0];
  const float* hp = (const float*)d_in[1];
  const float* Wz = (const float*)d_in[2];
  const float* Uz = (const float*)d_in[3];
  const float* bz = (const float*)d_in[4];
  const float* Wa = (const float*)d_in[5];
  const float* Ua = (const float*)d_in[6];
  const float* va = (const float*)d_in[7];
  const float* Wh = (const float*)d_in[8];
  const float* Uh = (const float*)d_in[9];
  const float* bh = (const float*)d_in[10];
  float* out = (float*)d_out;

  conv_w<<<dim3(192), dim3(256), 0, stream>>>(Wz, Uz, Wa, Ua, Wh, Uh);
  gru_fused<<<dim3(1024), dim3(BDIM), 0, stream>>>(x, hp, bz, va, bh, out);
}

// Round 7
// 406.623 us; speedup vs baseline: 1.1196x; 1.1196x over previous
//
#include <hip/hip_runtime.h>

typedef __attribute__((ext_vector_type(8))) short  short8v;
typedef __attribute__((ext_vector_type(4))) float  float4v;

#define BDIM 512

// Pre-converted, pre-swizzled bf16 weights: [p(3)][kb(8)][n(256)][c(8)][j(8)]
// content: B_p[n][kb*64 + (c ^ (n&7))*8 + j], B_p = [W_p | U_p] (K-concat, 512 wide)
__device__ ushort g_w[3 * 8 * 2048 * 8];

__device__ __forceinline__ ushort f2bf(float f) {
  unsigned u = __float_as_uint(f);
  u += 0x7fffu + ((u >> 16) & 1u);          // round-to-nearest-even
  return (ushort)(u >> 16);
}
__device__ __forceinline__ float bf2f(ushort s) {
  return __uint_as_float(((unsigned)s) << 16);
}

__global__ __launch_bounds__(256) void conv_w(
    const float* __restrict__ Wz, const float* __restrict__ Uz,
    const float* __restrict__ Wa, const float* __restrict__ Ua,
    const float* __restrict__ Wh, const float* __restrict__ Uh)
{
  int tid = blockIdx.x * 256 + threadIdx.x;   // 49152 total
  int p  = tid >> 14;
  int rm = tid & 16383;
  int kb = rm >> 11;
  int n  = (rm >> 3) & 255;
  int c  = rm & 7;
  const float* W = (p == 0) ? Wz : (p == 1) ? Wa : Wh;
  const float* U = (p == 0) ? Uz : (p == 1) ? Ua : Uh;
  int k0 = kb * 64 + ((c ^ (n & 7)) << 3);    // 8-aligned, never straddles 256
  const float* src = (k0 < 256) ? (W + n * 256 + k0) : (U + n * 256 + k0 - 256);
  uint pk[4];
#pragma unroll
  for (int jj = 0; jj < 4; ++jj) {
    float v0 = src[jj * 2], v1 = src[jj * 2 + 1];
    pk[jj] = (uint)f2bf(v0) | ((uint)f2bf(v1) << 16);
  }
  *reinterpret_cast<uint4*>(&g_w[(size_t)tid * 8]) = make_uint4(pk[0], pk[1], pk[2], pk[3]);
}

// Register diet: persistent state = acc(32) + packed z(16) + packed h(16);
// K-loop working set loaded per-s (afr 16 + bfr 8). Peak ~110 VGPR -> no
// spills at the allocator's 128 cap (rounds 3-5 spilled: WRITE_SIZE 290-427MB
// vs 64MB ideal).
__global__ __launch_bounds__(BDIM)
void gru_fused(
    const float* __restrict__ x,  const float* __restrict__ hp,
    const float* __restrict__ bz, const float* __restrict__ va,
    const float* __restrict__ bh, float* __restrict__ out)
{
  // A-tile: [64 rows][512 K] bf16, 16B-chunk XOR swizzle  (64 KB)
  __shared__ __align__(16) ushort sA[64 * 512];
  // B-tile: double-buffered [256 n][64 K] bf16, pre-swizzled in g_w  (2 x 32 KB)
  __shared__ __align__(16) ushort sB[2][256 * 64];
  __shared__ __align__(16) float  sRed[2][64 * 8];   // softmax cross-wave scratch

  const int tid  = threadIdx.x;
  const int w    = tid >> 6;       // wave 0..7, owns cols [w*32, w*32+32)
  const int lane = tid & 63;
  const int g4   = lane >> 4;
  const int l15  = lane & 15;
  const int sxor = l15 & 7;        // row&7 == n&7 == l15&7 for all frag rows
  const int rowBlk = blockIdx.x << 6;

  auto stageB = [&](int blkid, int buf) {
    const char* sb = (const char*)g_w + ((size_t)blkid << 15) + (w << 12) + (lane << 4);
    char* db = ((char*)&sB[buf][0]) + (w << 12);
#pragma unroll
    for (int i = 0; i < 4; ++i) {
      __builtin_amdgcn_global_load_lds(
          (const __attribute__((address_space(1))) void*)(sb + i * 1024),
          (__attribute__((address_space(3))) void*)(db + i * 1024),
          16, 0, 0);
    }
  };

  stageB(0, 0);   // phase 0, kb 0 -> buf 0

  { // stage A = [x | h] as bf16, swizzled
    const float4* xq = reinterpret_cast<const float4*>(x)  + (size_t)rowBlk * 64;
    const float4* hq = reinterpret_cast<const float4*>(hp) + (size_t)rowBlk * 64;
#pragma unroll
    for (int i = 0; i < 16; ++i) {
      int q   = tid + i * BDIM;        // 0..8191 quad index
      int row = q >> 7;
      int qc  = q & 127;
      float4 v = (qc < 64) ? xq[row * 64 + qc] : hq[row * 64 + qc - 64];
      int kE  = qc << 2;
      int swz = (kE >> 3) ^ (row & 7);
      ushort4 pk4;
      pk4.x = f2bf(v.x); pk4.y = f2bf(v.y); pk4.z = f2bf(v.z); pk4.w = f2bf(v.w);
      *reinterpret_cast<ushort4*>((char*)sA + (row << 10) + (swz << 4) + ((kE & 7) << 1)) = pk4;
    }
  }
  __syncthreads();   // full drain: sA + stage(0) complete

  float4v acc[4][2];
  uint    zp[4][2][2];   // z gate, bf16-packed pairs (j0|j1<<16),(j2|j3<<16)
  uint    hvp[4][2][2];  // h_prev at output positions, raw bf16 pairs
  int cur = 0;

  for (int p = 0; p < 3; ++p) {
#pragma unroll
    for (int m = 0; m < 4; ++m)
#pragma unroll
      for (int r = 0; r < 2; ++r)
        acc[m][r] = (float4v){0.f, 0.f, 0.f, 0.f};

    for (int kb = 0; kb < 8; ++kb) {
      int blk = p * 8 + kb;
      // Stage next K-block into cur^1 (its readers retired at the previous
      // s_barrier). Counted gate: keep the 4 just-issued loads in flight,
      // drain the 4 older ones that filled buffer `cur` (T4).
      if (blk < 23) {
        stageB(blk + 1, cur ^ 1);
        asm volatile("s_waitcnt vmcnt(4)" ::: "memory");
      } else {
        asm volatile("s_waitcnt vmcnt(0)" ::: "memory");
      }

#pragma unroll
      for (int s = 0; s < 2; ++s) {
        short8v afr[4], bfr[2];
#pragma unroll
        for (int m = 0; m < 4; ++m) {
          int row = m * 16 + l15;
          int swz = (kb * 8 + s * 4 + g4) ^ sxor;
          afr[m] = *reinterpret_cast<const short8v*>((const char*)sA + (row << 10) + (swz << 4));
        }
#pragma unroll
        for (int r = 0; r < 2; ++r) {
          int n   = (w << 5) + (r << 4) + l15;
          int swz = (s * 4 + g4) ^ sxor;
          bfr[r] = *reinterpret_cast<const short8v*>((const char*)&sB[cur][0] + (n << 7) + (swz << 4));
        }
#pragma unroll
        for (int m = 0; m < 4; ++m)
#pragma unroll
          for (int r = 0; r < 2; ++r)
            acc[m][r] = __builtin_amdgcn_mfma_f32_16x16x32_bf16(afr[m], bfr[r], acc[m][r], 0, 0, 0);
      }

      __builtin_amdgcn_s_barrier();   // window boundary (no vmcnt drain)
      cur ^= 1;
    }

    if (p == 0) {
      // z = sigmoid(pre + b_z), packed to bf16 pairs
#pragma unroll
      for (int r = 0; r < 2; ++r) {
        float b = bz[(w << 5) + (r << 4) + l15];
#pragma unroll
        for (int m = 0; m < 4; ++m)
#pragma unroll
          for (int jj = 0; jj < 2; ++jj) {
            float z0 = 1.f / (1.f + __expf(-(acc[m][r][2 * jj]     + b)));
            float z1 = 1.f / (1.f + __expf(-(acc[m][r][2 * jj + 1] + b)));
            zp[m][r][jj] = (uint)f2bf(z0) | ((uint)f2bf(z1) << 16);
          }
      }
    } else if (p == 1) {
      // t = tanh(pre) * v_a ; softmax over 256 cols per row ; attended = aw*h
      float vav[2];
      vav[0] = va[(w << 5) + l15];
      vav[1] = va[(w << 5) + 16 + l15];
#pragma unroll
      for (int m = 0; m < 4; ++m)
#pragma unroll
        for (int r = 0; r < 2; ++r)
#pragma unroll
          for (int j = 0; j < 4; ++j) {
            float s = acc[m][r][j];
            float t = 1.f - 2.f / (__expf(2.f * s) + 1.f);
            acc[m][r][j] = t * vav[r];
          }
      // wave-local row max (16-lane groups share a row set)
      float mx[4][4];
#pragma unroll
      for (int m = 0; m < 4; ++m)
#pragma unroll
        for (int j = 0; j < 4; ++j) {
          float v = fmaxf(acc[m][0][j], acc[m][1][j]);
          v = fmaxf(v, __shfl_xor(v, 1));
          v = fmaxf(v, __shfl_xor(v, 2));
          v = fmaxf(v, __shfl_xor(v, 4));
          v = fmaxf(v, __shfl_xor(v, 8));
          mx[m][j] = v;
        }
      if (l15 == 0) {
#pragma unroll
        for (int m = 0; m < 4; ++m)
#pragma unroll
          for (int j = 0; j < 4; ++j)
            sRed[0][((m * 16 + g4 * 4 + j) << 3) + w] = mx[m][j];
      }
      __syncthreads();
      float rmax[4][4];
#pragma unroll
      for (int m = 0; m < 4; ++m)
#pragma unroll
        for (int j = 0; j < 4; ++j) {
          int row = m * 16 + g4 * 4 + j;
          const float4* pr = reinterpret_cast<const float4*>(&sRed[0][row << 3]);
          float4 a = pr[0], b = pr[1];
          rmax[m][j] = fmaxf(fmaxf(fmaxf(a.x, a.y), fmaxf(a.z, a.w)),
                             fmaxf(fmaxf(b.x, b.y), fmaxf(b.z, b.w)));
        }
#pragma unroll
      for (int m = 0; m < 4; ++m)
#pragma unroll
        for (int j = 0; j < 4; ++j) {
          float e0 = __expf(acc[m][0][j] - rmax[m][j]);
          float e1 = __expf(acc[m][1][j] - rmax[m][j]);
          acc[m][0][j] = e0; acc[m][1][j] = e1;
          float sm = e0 + e1;
          sm += __shfl_xor(sm, 1);
          sm += __shfl_xor(sm, 2);
          sm += __shfl_xor(sm, 4);
          sm += __shfl_xor(sm, 8);
          if (l15 == 0) sRed[1][((m * 16 + g4 * 4 + j) << 3) + w] = sm;
        }
      // capture h (own output positions, raw bf16) BEFORE overwrite
#pragma unroll
      for (int m = 0; m < 4; ++m)
#pragma unroll
        for (int r = 0; r < 2; ++r)
#pragma unroll
          for (int jj = 0; jj < 2; ++jj) {
            int row0 = m * 16 + g4 * 4 + 2 * jj;
            int row1 = row0 + 1;
            int cs0  = (32 + (w << 2) + (r << 1) + (l15 >> 3)) ^ (row0 & 7);
            int cs1  = (32 + (w << 2) + (r << 1) + (l15 >> 3)) ^ (row1 & 7);
            uint h0 = sA[(row0 << 9) + (cs0 << 3) + sxor];
            uint h1 = sA[(row1 << 9) + (cs1 << 3) + sxor];
            hvp[m][r][jj] = h0 | (h1 << 16);
          }
      __syncthreads();
#pragma unroll
      for (int m = 0; m < 4; ++m)
#pragma unroll
        for (int j = 0; j < 4; ++j) {
          int row = m * 16 + g4 * 4 + j;
          const float4* pr = reinterpret_cast<const float4*>(&sRed[1][row << 3]);
          float4 a = pr[0], b = pr[1];
          float s = (a.x + a.y) + (a.z + a.w) + (b.x + b.y) + (b.z + b.w);
          float inv = 1.f / s;
#pragma unroll
          for (int r = 0; r < 2; ++r) {
            uint hw = hvp[m][r][j >> 1];
            float hval = bf2f((ushort)((j & 1) ? (hw >> 16) : (hw & 0xffffu)));
            float at = acc[m][r][j] * inv * hval;
            int cs = (32 + (w << 2) + (r << 1) + (l15 >> 3)) ^ (row & 7);
            sA[(row << 9) + (cs << 3) + sxor] = f2bf(at);
          }
        }
      __syncthreads();
    } else {
      // h~ = tanh(pre + b_h); h_t = (1-z)h + z h~
#pragma unroll
      for (int r = 0; r < 2; ++r) {
        float b = bh[(w << 5) + (r << 4) + l15];
#pragma unroll
        for (int m = 0; m < 4; ++m)
#pragma unroll
          for (int j = 0; j < 4; ++j) {
            float s  = acc[m][r][j] + b;
            float ht = 1.f - 2.f / (__expf(2.f * s) + 1.f);
            uint zw  = zp[m][r][j >> 1];
            float z  = bf2f((ushort)((j & 1) ? (zw >> 16) : (zw & 0xffffu)));
            uint hw  = hvp[m][r][j >> 1];
            float h0 = bf2f((ushort)((j & 1) ? (hw >> 16) : (hw & 0xffffu)));
            float res = (1.f - z) * h0 + z * ht;
            int row = m * 16 + g4 * 4 + j;
            out[(size_t)(rowBlk + row) * 256 + (w << 5) + (r << 4) + l15] = res;
          }
      }
    }
  }
}

extern "C" void kernel_launch(void* const* d_in, const int* in_sizes, int n_in,
                              void* d_out, int out_size, void* d_ws, size_t ws_size,
                              hipStream_t stream)
{
  const float* x  = (const float*)d_in[0];
  const float* hp = (const float*)d_in[1];
  const float* Wz = (const float*)d_in[2];
  const float* Uz = (const float*)d_in[3];
  const float* bz = (const float*)d_in[4];
  const float* Wa = (const float*)d_in[5];
  const float* Ua = (const float*)d_in[6];
  const float* va = (const float*)d_in[7];
  const float* Wh = (const float*)d_in[8];
  const float* Uh = (const float*)d_in[9];
  const float* bh = (const float*)d_in[10];
  float* out = (float*)d_out;

  conv_w<<<dim3(192), dim3(256), 0, stream>>>(Wz, Uz, Wa, Ua, Wh, Uh);
  gru_fused<<<dim3(1024), dim3(BDIM), 0, stream>>>(x, hp, bz, va, bh, out);
}

// Round 8
// 373.427 us; speedup vs baseline: 1.2192x; 1.0889x over previous
//
#include <hip/hip_runtime.h>

typedef __attribute__((ext_vector_type(8))) short  short8v;
typedef __attribute__((ext_vector_type(4))) float  float4v;

#define BDIM 512

// bf16 weights pre-arranged in MFMA B-fragment order, 1KB chunks:
// chunk index c = ((p*8 + kb)*16 + c16)*2 + s    (p:3, kb:8, c16:16, s:2)
// lane l (0..63) holds 8 bf16: B_p[c16*16 + (l&15)][kb*64 + s*32 + (l>>4)*8 + j]
// where B_p = [W_p | U_p] K-concatenated (512 wide), W rows = output cols.
// (verified correct in round 4: absmax 0.03125)
__device__ ushort g_w[3 * 8 * 16 * 2 * 64 * 8];   // 768 KB

__device__ __forceinline__ ushort f2bf(float f) {
  unsigned u = __float_as_uint(f);
  u += 0x7fffu + ((u >> 16) & 1u);          // round-to-nearest-even
  return (ushort)(u >> 16);
}
__device__ __forceinline__ float bf2f(ushort s) {
  return __uint_as_float(((unsigned)s) << 16);
}

__global__ __launch_bounds__(256) void conv_w(
    const float* __restrict__ Wz, const float* __restrict__ Uz,
    const float* __restrict__ Wa, const float* __restrict__ Ua,
    const float* __restrict__ Wh, const float* __restrict__ Uh)
{
  int tid = blockIdx.x * 256 + threadIdx.x;   // 49152 total = one lane-slot each
  int p   = tid >> 14;
  int kb  = (tid >> 11) & 7;
  int c16 = (tid >> 7) & 15;
  int s   = (tid >> 6) & 1;
  int l   = tid & 63;
  const float* W = (p == 0) ? Wz : (p == 1) ? Wa : Wh;
  const float* U = (p == 0) ? Uz : (p == 1) ? Ua : Uh;
  int col = c16 * 16 + (l & 15);              // output column (weight row)
  int k0  = kb * 64 + s * 32 + ((l >> 4) << 3);  // 8-aligned, never straddles 256
  const float* src = (k0 < 256) ? (W + col * 256 + k0) : (U + col * 256 + (k0 - 256));
  uint pk[4];
#pragma unroll
  for (int jj = 0; jj < 4; ++jj) {
    float v0 = src[jj * 2], v1 = src[jj * 2 + 1];
    pk[jj] = (uint)f2bf(v0) | ((uint)f2bf(v1) << 16);
  }
  *reinterpret_cast<uint4*>(&g_w[(size_t)tid * 8]) = make_uint4(pk[0], pk[1], pk[2], pk[3]);
}

// Design (round 8): no sB, no global_load_lds, no K-loop barriers.
// B-fragments stream global->VGPR (L2-resident, parity double-buffer, K=32
// steps). LDS = sA 64KB + sRed 4KB = 68KB -> 2 WG/CU -> 4 waves/SIMD.
// Register diet (packed zp/hvp) keeps peak ~110 VGPR under the 128 cap
// that 4 waves/SIMD requires.
__global__ __launch_bounds__(BDIM)
void gru_fused(
    const float* __restrict__ x,  const float* __restrict__ hp,
    const float* __restrict__ bz, const float* __restrict__ va,
    const float* __restrict__ bh, float* __restrict__ out)
{
  // A-tile: [64 rows][512 K] bf16, 16B-chunk XOR swizzle  (64 KB)
  __shared__ __align__(16) ushort sA[64 * 512];
  __shared__ __align__(16) float  sRed[2][64 * 8];   // softmax cross-wave scratch

  const int tid  = threadIdx.x;
  const int w    = tid >> 6;       // wave 0..7, owns cols [w*32, w*32+32)
  const int lane = tid & 63;
  const int g4   = lane >> 4;
  const int l15  = lane & 15;
  const int sxor = l15 & 7;        // row&7 == n&7 == l15&7 for all frag rows
  const int rowBlk = blockIdx.x << 6;

  // B-fragment stream: wave w's chunks are c16 = w*2 + r.
  // byte layout: chunk 1KB; ushort offset = ((p*8+kb)*32 + (w*2+r)*2 + s)*512 + lane*8
  const ushort* wbase = g_w + (size_t)(w * 2048) + (size_t)lane * 8;
  short8v bB[2][2];                // [parity][r]
  auto loadBs = [&](int t, short8v* b) {    // t = global step = p*16 + kb*2 + s
    const ushort* pb = wbase + ((size_t)(t >> 1) << 14) + (size_t)((t & 1) << 9);
    b[0] = *reinterpret_cast<const short8v*>(pb);
    b[1] = *reinterpret_cast<const short8v*>(pb + 1024);
  };

  loadBs(0, bB[0]);   // first step in flight under the A-stage

  { // stage A = [x | h] as bf16, swizzled
    const float4* xq = reinterpret_cast<const float4*>(x)  + (size_t)rowBlk * 64;
    const float4* hq = reinterpret_cast<const float4*>(hp) + (size_t)rowBlk * 64;
#pragma unroll
    for (int i = 0; i < 16; ++i) {
      int q   = tid + i * BDIM;        // 0..8191 quad index
      int row = q >> 7;
      int qc  = q & 127;
      float4 v = (qc < 64) ? xq[row * 64 + qc] : hq[row * 64 + qc - 64];
      int kE  = qc << 2;
      int swz = (kE >> 3) ^ (row & 7);
      ushort4 pk4;
      pk4.x = f2bf(v.x); pk4.y = f2bf(v.y); pk4.z = f2bf(v.z); pk4.w = f2bf(v.w);
      *reinterpret_cast<ushort4*>((char*)sA + (row << 10) + (swz << 4) + ((kE & 7) << 1)) = pk4;
    }
  }
  __syncthreads();   // sA ready; sA is read-only until the phase-1 epilogue

  float4v acc[4][2];
  uint    zp[4][2][2];   // z gate, bf16-packed pairs (j0|j1<<16),(j2|j3<<16)
  uint    hvp[4][2][2];  // h_prev at output positions, raw bf16 pairs

  for (int p = 0; p < 3; ++p) {
#pragma unroll
    for (int m = 0; m < 4; ++m)
#pragma unroll
      for (int r = 0; r < 2; ++r)
        acc[m][r] = (float4v){0.f, 0.f, 0.f, 0.f};

    // Barrier-free K-loop, 16 steps of K=32. Step st consumes bB[s], and
    // prefetches st+1 into bB[s^1] (consumed next step) — compiler sees the
    // exact register dependence and overlaps the L2 load with ds_read+MFMA.
#pragma unroll
    for (int kb = 0; kb < 8; ++kb) {
#pragma unroll
      for (int s = 0; s < 2; ++s) {
        if ((kb * 2 + s < 15) || (p < 2))
          loadBs(p * 16 + kb * 2 + s + 1, bB[s ^ 1]);
        short8v afr[4];
#pragma unroll
        for (int m = 0; m < 4; ++m) {
          int row = m * 16 + l15;
          int swz = (kb * 8 + s * 4 + g4) ^ sxor;
          afr[m] = *reinterpret_cast<const short8v*>((const char*)sA + (row << 10) + (swz << 4));
        }
#pragma unroll
        for (int m = 0; m < 4; ++m)
#pragma unroll
          for (int r = 0; r < 2; ++r)
            acc[m][r] = __builtin_amdgcn_mfma_f32_16x16x32_bf16(afr[m], bB[s][r], acc[m][r], 0, 0, 0);
      }
    }

    if (p == 0) {
      // z = sigmoid(pre + b_z), packed to bf16 pairs
#pragma unroll
      for (int r = 0; r < 2; ++r) {
        float b = bz[(w << 5) + (r << 4) + l15];
#pragma unroll
        for (int m = 0; m < 4; ++m)
#pragma unroll
          for (int jj = 0; jj < 2; ++jj) {
            float z0 = 1.f / (1.f + __expf(-(acc[m][r][2 * jj]     + b)));
            float z1 = 1.f / (1.f + __expf(-(acc[m][r][2 * jj + 1] + b)));
            zp[m][r][jj] = (uint)f2bf(z0) | ((uint)f2bf(z1) << 16);
          }
      }
    } else if (p == 1) {
      // t = tanh(pre) * v_a ; softmax over 256 cols per row ; attended = aw*h
      float vav[2];
      vav[0] = va[(w << 5) + l15];
      vav[1] = va[(w << 5) + 16 + l15];
#pragma unroll
      for (int m = 0; m < 4; ++m)
#pragma unroll
        for (int r = 0; r < 2; ++r)
#pragma unroll
          for (int j = 0; j < 4; ++j) {
            float s = acc[m][r][j];
            float t = 1.f - 2.f / (__expf(2.f * s) + 1.f);
            acc[m][r][j] = t * vav[r];
          }
      // wave-local row max (16-lane groups share a row set)
      float mx[4][4];
#pragma unroll
      for (int m = 0; m < 4; ++m)
#pragma unroll
        for (int j = 0; j < 4; ++j) {
          float v = fmaxf(acc[m][0][j], acc[m][1][j]);
          v = fmaxf(v, __shfl_xor(v, 1));
          v = fmaxf(v, __shfl_xor(v, 2));
          v = fmaxf(v, __shfl_xor(v, 4));
          v = fmaxf(v, __shfl_xor(v, 8));
          mx[m][j] = v;
        }
      if (l15 == 0) {
#pragma unroll
        for (int m = 0; m < 4; ++m)
#pragma unroll
          for (int j = 0; j < 4; ++j)
            sRed[0][((m * 16 + g4 * 4 + j) << 3) + w] = mx[m][j];
      }
      __syncthreads();   // also: all waves done with phase-1 K-loop reads
      float rmax[4][4];
#pragma unroll
      for (int m = 0; m < 4; ++m)
#pragma unroll
        for (int j = 0; j < 4; ++j) {
          int row = m * 16 + g4 * 4 + j;
          const float4* pr = reinterpret_cast<const float4*>(&sRed[0][row << 3]);
          float4 a = pr[0], b = pr[1];
          rmax[m][j] = fmaxf(fmaxf(fmaxf(a.x, a.y), fmaxf(a.z, a.w)),
                             fmaxf(fmaxf(b.x, b.y), fmaxf(b.z, b.w)));
        }
#pragma unroll
      for (int m = 0; m < 4; ++m)
#pragma unroll
        for (int j = 0; j < 4; ++j) {
          float e0 = __expf(acc[m][0][j] - rmax[m][j]);
          float e1 = __expf(acc[m][1][j] - rmax[m][j]);
          acc[m][0][j] = e0; acc[m][1][j] = e1;
          float sm = e0 + e1;
          sm += __shfl_xor(sm, 1);
          sm += __shfl_xor(sm, 2);
          sm += __shfl_xor(sm, 4);
          sm += __shfl_xor(sm, 8);
          if (l15 == 0) sRed[1][((m * 16 + g4 * 4 + j) << 3) + w] = sm;
        }
      // capture h (own output positions, raw bf16) BEFORE overwrite
#pragma unroll
      for (int m = 0; m < 4; ++m)
#pragma unroll
        for (int r = 0; r < 2; ++r)
#pragma unroll
          for (int jj = 0; jj < 2; ++jj) {
            int row0 = m * 16 + g4 * 4 + 2 * jj;
            int row1 = row0 + 1;
            int cs0  = (32 + (w << 2) + (r << 1) + (l15 >> 3)) ^ (row0 & 7);
            int cs1  = (32 + (w << 2) + (r << 1) + (l15 >> 3)) ^ (row1 & 7);
            uint h0 = sA[(row0 << 9) + (cs0 << 3) + sxor];
            uint h1 = sA[(row1 << 9) + (cs1 << 3) + sxor];
            hvp[m][r][jj] = h0 | (h1 << 16);
          }
      __syncthreads();   // everyone captured h; sum scratch ready
#pragma unroll
      for (int m = 0; m < 4; ++m)
#pragma unroll
        for (int j = 0; j < 4; ++j) {
          int row = m * 16 + g4 * 4 + j;
          const float4* pr = reinterpret_cast<const float4*>(&sRed[1][row << 3]);
          float4 a = pr[0], b = pr[1];
          float s = (a.x + a.y) + (a.z + a.w) + (b.x + b.y) + (b.z + b.w);
          float inv = 1.f / s;
#pragma unroll
          for (int r = 0; r < 2; ++r) {
            uint hw = hvp[m][r][j >> 1];
            float hval = bf2f((ushort)((j & 1) ? (hw >> 16) : (hw & 0xffffu)));
            float at = acc[m][r][j] * inv * hval;
            int cs = (32 + (w << 2) + (r << 1) + (l15 >> 3)) ^ (row & 7);
            sA[(row << 9) + (cs << 3) + sxor] = f2bf(at);
          }
        }
      __syncthreads();   // attended in sA; safe for phase-2 K-loop
    } else {
      // h~ = tanh(pre + b_h); h_t = (1-z)h + z h~
#pragma unroll
      for (int r = 0; r < 2; ++r) {
        float b = bh[(w << 5) + (r << 4) + l15];
#pragma unroll
        for (int m = 0; m < 4; ++m)
#pragma unroll
          for (int j = 0; j < 4; ++j) {
            float s  = acc[m][r][j] + b;
            float ht = 1.f - 2.f / (__expf(2.f * s) + 1.f);
            uint zw  = zp[m][r][j >> 1];
            float z  = bf2f((ushort)((j & 1) ? (zw >> 16) : (zw & 0xffffu)));
            uint hw  = hvp[m][r][j >> 1];
            float h0 = bf2f((ushort)((j & 1) ? (hw >> 16) : (hw & 0xffffu)));
            float res = (1.f - z) * h0 + z * ht;
            int row = m * 16 + g4 * 4 + j;
            out[(size_t)(rowBlk + row) * 256 + (w << 5) + (r << 4) + l15] = res;
          }
      }
    }
  }
}

extern "C" void kernel_launch(void* const* d_in, const int* in_sizes, int n_in,
                              void* d_out, int out_size, void* d_ws, size_t ws_size,
                              hipStream_t stream)
{
  const float* x  = (const float*)d_in[0];
  const float* hp = (const float*)d_in[1];
  const float* Wz = (const float*)d_in[2];
  const float* Uz = (const float*)d_in[3];
  const float* bz = (const float*)d_in[4];
  const float* Wa = (const float*)d_in[5];
  const float* Ua = (const float*)d_in[6];
  const float* va = (const float*)d_in[7];
  const float* Wh = (const float*)d_in[8];
  const float* Uh = (const float*)d_in[9];
  const float* bh = (const float*)d_in[10];
  float* out = (float*)d_out;

  conv_w<<<dim3(192), dim3(256), 0, stream>>>(Wz, Uz, Wa, Ua, Wh, Uh);
  gru_fused<<<dim3(1024), dim3(BDIM), 0, stream>>>(x, hp, bz, va, bh, out);
}

// Round 9
// 348.014 us; speedup vs baseline: 1.3082x; 1.0730x over previous
//
#include <hip/hip_runtime.h>

typedef __attribute__((ext_vector_type(8))) short  short8v;
typedef __attribute__((ext_vector_type(4))) float  float4v;

#define BDIM 512

// bf16 weights pre-arranged in MFMA B-fragment order, 1KB chunks:
// ushort offset = (((p*8+kb)*16 + c16)*2 + s)*512 + lane*8
// lane l holds 8 bf16: B_p[c16*16 + (l&15)][kb*64 + s*32 + (l>>4)*8 + j]
// B_p = [W_p | U_p] K-concatenated (512 wide). (verified: rounds 4/7/8)
__device__ ushort g_w[3 * 8 * 16 * 2 * 64 * 8];   // 768 KB

__device__ __forceinline__ ushort f2bf(float f) {
  unsigned u = __float_as_uint(f);
  u += 0x7fffu + ((u >> 16) & 1u);          // round-to-nearest-even
  return (ushort)(u >> 16);
}
__device__ __forceinline__ float bf2f(ushort s) {
  return __uint_as_float(((unsigned)s) << 16);
}

__global__ __launch_bounds__(256) void conv_w(
    const float* __restrict__ Wz, const float* __restrict__ Uz,
    const float* __restrict__ Wa, const float* __restrict__ Ua,
    const float* __restrict__ Wh, const float* __restrict__ Uh)
{
  int tid = blockIdx.x * 256 + threadIdx.x;   // 49152 total = one lane-slot each
  int p   = tid >> 14;
  int kb  = (tid >> 11) & 7;
  int c16 = (tid >> 7) & 15;
  int s   = (tid >> 6) & 1;
  int l   = tid & 63;
  const float* W = (p == 0) ? Wz : (p == 1) ? Wa : Wh;
  const float* U = (p == 0) ? Uz : (p == 1) ? Ua : Uh;
  int col = c16 * 16 + (l & 15);              // output column (weight row)
  int k0  = kb * 64 + s * 32 + ((l >> 4) << 3);  // 8-aligned, never straddles 256
  const float* src = (k0 < 256) ? (W + col * 256 + k0) : (U + col * 256 + (k0 - 256));
  uint pk[4];
#pragma unroll
  for (int jj = 0; jj < 4; ++jj) {
    float v0 = src[jj * 2], v1 = src[jj * 2 + 1];
    pk[jj] = (uint)f2bf(v0) | ((uint)f2bf(v1) << 16);
  }
  *reinterpret_cast<uint4*>(&g_w[(size_t)tid * 8]) = make_uint4(pk[0], pk[1], pk[2], pk[3]);
}

// Round 9: force 4 waves/EU (total VGPR+AGPR <= 128 -> 2 WG/CU) and merge
// the z/attention GEMMs into one K-loop (shared A-fragments: 16 MFMA per
// afr load). Hot-loop regs: accZ32+accA32+bZ16+bA16+afr16 ~= 124.
__global__ __launch_bounds__(BDIM, 4)
void gru_fused(
    const float* __restrict__ x,  const float* __restrict__ hp,
    const float* __restrict__ bz, const float* __restrict__ va,
    const float* __restrict__ bh, float* __restrict__ out)
{
  // A-tile: [64 rows][512 K] bf16, 16B-chunk XOR swizzle  (64 KB)
  __shared__ __align__(16) ushort sA[64 * 512];
  __shared__ __align__(16) float  sRed[2][64 * 8];   // softmax cross-wave scratch

  const int tid  = threadIdx.x;
  const int w    = tid >> 6;       // wave 0..7, owns cols [w*32, w*32+32)
  const int lane = tid & 63;
  const int g4   = lane >> 4;
  const int l15  = lane & 15;
  const int sxor = l15 & 7;        // row&7 == n&7 == l15&7 for all frag rows
  const int rowBlk = blockIdx.x << 6;

  // B-fragment stream: wave w's chunks are c16 = w*2 + r.
  const ushort* wbase = g_w + (size_t)(w * 2048) + (size_t)lane * 8;
  short8v bZ[2][2], bA[2][2], bH[2][2];        // [parity][r]
  auto loadS = [&](int p, int t, short8v* b) { // t = kb*2 + s
    const ushort* pb = wbase + (size_t)p * 131072
                     + ((size_t)(t >> 1) << 14) + ((size_t)(t & 1) << 9);
    b[0] = *reinterpret_cast<const short8v*>(pb);
    b[1] = *reinterpret_cast<const short8v*>(pb + 1024);
  };

  loadS(0, 0, bZ[0]);   // first step of both merged streams in flight
  loadS(1, 0, bA[0]);

  { // stage A = [x | h] as bf16, swizzled
    const float4* xq = reinterpret_cast<const float4*>(x)  + (size_t)rowBlk * 64;
    const float4* hq = reinterpret_cast<const float4*>(hp) + (size_t)rowBlk * 64;
#pragma unroll
    for (int i = 0; i < 16; ++i) {
      int q   = tid + i * BDIM;        // 0..8191 quad index
      int row = q >> 7;
      int qc  = q & 127;
      float4 v = (qc < 64) ? xq[row * 64 + qc] : hq[row * 64 + qc - 64];
      int kE  = qc << 2;
      int swz = (kE >> 3) ^ (row & 7);
      ushort4 pk4;
      pk4.x = f2bf(v.x); pk4.y = f2bf(v.y); pk4.z = f2bf(v.z); pk4.w = f2bf(v.w);
      *reinterpret_cast<ushort4*>((char*)sA + (row << 10) + (swz << 4) + ((kE & 7) << 1)) = pk4;
    }
  }
  __syncthreads();   // sA ready; read-only until the attention epilogue

  float4v accZ[4][2], accA[4][2];
#pragma unroll
  for (int m = 0; m < 4; ++m)
#pragma unroll
    for (int r = 0; r < 2; ++r) {
      accZ[m][r] = (float4v){0.f, 0.f, 0.f, 0.f};
      accA[m][r] = (float4v){0.f, 0.f, 0.f, 0.f};
    }

  // ---- merged K-loop: z-GEMM + attention-GEMM share afr ----
#pragma unroll
  for (int kb = 0; kb < 8; ++kb)
#pragma unroll
    for (int s = 0; s < 2; ++s) {
      const int t = kb * 2 + s;
      if (t < 15) { loadS(0, t + 1, bZ[s ^ 1]); loadS(1, t + 1, bA[s ^ 1]); }
      else        { loadS(2, 0, bH[0]); }   // prefetch candidate stream
      short8v afr[4];
#pragma unroll
      for (int m = 0; m < 4; ++m) {
        int row = m * 16 + l15;
        int swz = (kb * 8 + s * 4 + g4) ^ sxor;
        afr[m] = *reinterpret_cast<const short8v*>((const char*)sA + (row << 10) + (swz << 4));
      }
#pragma unroll
      for (int m = 0; m < 4; ++m)
#pragma unroll
        for (int r = 0; r < 2; ++r) {
          accZ[m][r] = __builtin_amdgcn_mfma_f32_16x16x32_bf16(afr[m], bZ[s][r], accZ[m][r], 0, 0, 0);
          accA[m][r] = __builtin_amdgcn_mfma_f32_16x16x32_bf16(afr[m], bA[s][r], accA[m][r], 0, 0, 0);
        }
    }

  // ---- z epilogue: z = sigmoid(pre + b_z), bf16-packed ----
  uint zp[4][2][2];
#pragma unroll
  for (int r = 0; r < 2; ++r) {
    float b = bz[(w << 5) + (r << 4) + l15];
#pragma unroll
    for (int m = 0; m < 4; ++m)
#pragma unroll
      for (int jj = 0; jj < 2; ++jj) {
        float z0 = 1.f / (1.f + __expf(-(accZ[m][r][2 * jj]     + b)));
        float z1 = 1.f / (1.f + __expf(-(accZ[m][r][2 * jj + 1] + b)));
        zp[m][r][jj] = (uint)f2bf(z0) | ((uint)f2bf(z1) << 16);
      }
  }

  // ---- attention epilogue: tanh*v_a, row-softmax, attended -> sA ----
  uint hvp[4][2][2];
  {
    float vav[2];
    vav[0] = va[(w << 5) + l15];
    vav[1] = va[(w << 5) + 16 + l15];
#pragma unroll
    for (int m = 0; m < 4; ++m)
#pragma unroll
      for (int r = 0; r < 2; ++r)
#pragma unroll
        for (int j = 0; j < 4; ++j) {
          float s = accA[m][r][j];
          float t = 1.f - 2.f / (__expf(2.f * s) + 1.f);
          accA[m][r][j] = t * vav[r];
        }
    float mx[4][4];
#pragma unroll
    for (int m = 0; m < 4; ++m)
#pragma unroll
      for (int j = 0; j < 4; ++j) {
        float v = fmaxf(accA[m][0][j], accA[m][1][j]);
        v = fmaxf(v, __shfl_xor(v, 1));
        v = fmaxf(v, __shfl_xor(v, 2));
        v = fmaxf(v, __shfl_xor(v, 4));
        v = fmaxf(v, __shfl_xor(v, 8));
        mx[m][j] = v;
      }
    if (l15 == 0) {
#pragma unroll
      for (int m = 0; m < 4; ++m)
#pragma unroll
        for (int j = 0; j < 4; ++j)
          sRed[0][((m * 16 + g4 * 4 + j) << 3) + w] = mx[m][j];
    }
    __syncthreads();
    float rmax[4][4];
#pragma unroll
    for (int m = 0; m < 4; ++m)
#pragma unroll
      for (int j = 0; j < 4; ++j) {
        int row = m * 16 + g4 * 4 + j;
        const float4* pr = reinterpret_cast<const float4*>(&sRed[0][row << 3]);
        float4 a = pr[0], b = pr[1];
        rmax[m][j] = fmaxf(fmaxf(fmaxf(a.x, a.y), fmaxf(a.z, a.w)),
                           fmaxf(fmaxf(b.x, b.y), fmaxf(b.z, b.w)));
      }
#pragma unroll
    for (int m = 0; m < 4; ++m)
#pragma unroll
      for (int j = 0; j < 4; ++j) {
        float e0 = __expf(accA[m][0][j] - rmax[m][j]);
        float e1 = __expf(accA[m][1][j] - rmax[m][j]);
        accA[m][0][j] = e0; accA[m][1][j] = e1;
        float sm = e0 + e1;
        sm += __shfl_xor(sm, 1);
        sm += __shfl_xor(sm, 2);
        sm += __shfl_xor(sm, 4);
        sm += __shfl_xor(sm, 8);
        if (l15 == 0) sRed[1][((m * 16 + g4 * 4 + j) << 3) + w] = sm;
      }
    // capture h (own output positions, raw bf16) BEFORE overwrite
#pragma unroll
    for (int m = 0; m < 4; ++m)
#pragma unroll
      for (int r = 0; r < 2; ++r)
#pragma unroll
        for (int jj = 0; jj < 2; ++jj) {
          int row0 = m * 16 + g4 * 4 + 2 * jj;
          int row1 = row0 + 1;
          int cs0  = (32 + (w << 2) + (r << 1) + (l15 >> 3)) ^ (row0 & 7);
          int cs1  = (32 + (w << 2) + (r << 1) + (l15 >> 3)) ^ (row1 & 7);
          uint h0 = sA[(row0 << 9) + (cs0 << 3) + sxor];
          uint h1 = sA[(row1 << 9) + (cs1 << 3) + sxor];
          hvp[m][r][jj] = h0 | (h1 << 16);
        }
    __syncthreads();   // all h captured; sum scratch ready
#pragma unroll
    for (int m = 0; m < 4; ++m)
#pragma unroll
      for (int j = 0; j < 4; ++j) {
        int row = m * 16 + g4 * 4 + j;
        const float4* pr = reinterpret_cast<const float4*>(&sRed[1][row << 3]);
        float4 a = pr[0], b = pr[1];
        float s = (a.x + a.y) + (a.z + a.w) + (b.x + b.y) + (b.z + b.w);
        float inv = 1.f / s;
#pragma unroll
        for (int r = 0; r < 2; ++r) {
          uint hw = hvp[m][r][j >> 1];
          float hval = bf2f((ushort)((j & 1) ? (hw >> 16) : (hw & 0xffffu)));
          float at = accA[m][r][j] * inv * hval;
          int cs = (32 + (w << 2) + (r << 1) + (l15 >> 3)) ^ (row & 7);
          sA[(row << 9) + (cs << 3) + sxor] = f2bf(at);
        }
      }
    __syncthreads();   // attended in sA; safe for candidate K-loop
  }

  // ---- candidate K-loop: h~ GEMM ----
  float4v accH[4][2];
#pragma unroll
  for (int m = 0; m < 4; ++m)
#pragma unroll
    for (int r = 0; r < 2; ++r)
      accH[m][r] = (float4v){0.f, 0.f, 0.f, 0.f};
#pragma unroll
  for (int kb = 0; kb < 8; ++kb)
#pragma unroll
    for (int s = 0; s < 2; ++s) {
      const int t = kb * 2 + s;
      if (t < 15) loadS(2, t + 1, bH[s ^ 1]);
      short8v afr[4];
#pragma unroll
      for (int m = 0; m < 4; ++m) {
        int row = m * 16 + l15;
        int swz = (kb * 8 + s * 4 + g4) ^ sxor;
        afr[m] = *reinterpret_cast<const short8v*>((const char*)sA + (row << 10) + (swz << 4));
      }
#pragma unroll
      for (int m = 0; m < 4; ++m)
#pragma unroll
        for (int r = 0; r < 2; ++r)
          accH[m][r] = __builtin_amdgcn_mfma_f32_16x16x32_bf16(afr[m], bH[s][r], accH[m][r], 0, 0, 0);
    }

  // ---- final: h~ = tanh(pre + b_h); h_t = (1-z)h + z h~ ----
#pragma unroll
  for (int r = 0; r < 2; ++r) {
    float b = bh[(w << 5) + (r << 4) + l15];
#pragma unroll
    for (int m = 0; m < 4; ++m)
#pragma unroll
      for (int j = 0; j < 4; ++j) {
        float s  = accH[m][r][j] + b;
        float ht = 1.f - 2.f / (__expf(2.f * s) + 1.f);
        uint zw  = zp[m][r][j >> 1];
        float z  = bf2f((ushort)((j & 1) ? (zw >> 16) : (zw & 0xffffu)));
        uint hw  = hvp[m][r][j >> 1];
        float h0 = bf2f((ushort)((j & 1) ? (hw >> 16) : (hw & 0xffffu)));
        float res = (1.f - z) * h0 + z * ht;
        int row = m * 16 + g4 * 4 + j;
        out[(size_t)(rowBlk + row) * 256 + (w << 5) + (r << 4) + l15] = res;
      }
  }
}

extern "C" void kernel_launch(void* const* d_in, const int* in_sizes, int n_in,
                              void* d_out, int out_size, void* d_ws, size_t ws_size,
                              hipStream_t stream)
{
  const float* x  = (const float*)d_in[0];
  const float* hp = (const float*)d_in[1];
  const float* Wz = (const float*)d_in[2];
  const float* Uz = (const float*)d_in[3];
  const float* bz = (const float*)d_in[4];
  const float* Wa = (const float*)d_in[5];
  const float* Ua = (const float*)d_in[6];
  const float* va = (const float*)d_in[7];
  const float* Wh = (const float*)d_in[8];
  const float* Uh = (const float*)d_in[9];
  const float* bh = (const float*)d_in[10];
  float* out = (float*)d_out;

  conv_w<<<dim3(192), dim3(256), 0, stream>>>(Wz, Uz, Wa, Ua, Wh, Uh);
  gru_fused<<<dim3(1024), dim3(BDIM), 0, stream>>>(x, hp, bz, va, bh, out);
}